// Round 4
// baseline (124.397 us; speedup 1.0000x reference)
//
#include <hip/hip_runtime.h>

// Problem dims (fixed by setup_inputs)
#define BS 8
#define NF 16
#define NI 24
#define LL 16384   // 128*128

// Workspace layout (floats)
#define OFF_COUNTS 0                 // [BS][NI]        192
#define OFF_SUMS   192               // [BS][NI][NF]   3072
#define OFF_VNUM   3264              // [BS]
#define WS_ZERO_FLOATS 3272

#define L_CHUNKS 32   // k_sums chunks per batch (512 px each)
#define I_PER 3       // instances per wave (8 waves x 3 = 24)

// Full 64-lane sum via DPP (VALU only, no LDS pipe). Result valid in lane 63.
__device__ __forceinline__ float wave_sum63(float v) {
    v += __int_as_float(__builtin_amdgcn_update_dpp(0, __float_as_int(v), 0x111, 0xf, 0xf, true)); // row_shr:1
    v += __int_as_float(__builtin_amdgcn_update_dpp(0, __float_as_int(v), 0x112, 0xf, 0xf, true)); // row_shr:2
    v += __int_as_float(__builtin_amdgcn_update_dpp(0, __float_as_int(v), 0x114, 0xf, 0xf, true)); // row_shr:4
    v += __int_as_float(__builtin_amdgcn_update_dpp(0, __float_as_int(v), 0x118, 0xf, 0xf, true)); // row_shr:8
    v += __int_as_float(__builtin_amdgcn_update_dpp(0, __float_as_int(v), 0x142, 0xa, 0xf, true)); // row_bcast:15
    v += __int_as_float(__builtin_amdgcn_update_dpp(0, __float_as_int(v), 0x143, 0xc, 0xf, true)); // row_bcast:31
    return v;
}

__device__ __forceinline__ float block_sum(float v, volatile float* red) {
    for (int off = 32; off; off >>= 1) v += __shfl_down(v, off);
    __syncthreads();
    if ((threadIdx.x & 63) == 0) red[threadIdx.x >> 6] = v;
    __syncthreads();
    float r = 0.f;
    int nw = blockDim.x >> 6;
    if ((int)threadIdx.x < nw) r = red[threadIdx.x];
    if ((threadIdx.x >> 6) == 0)
        for (int off = 32; off; off >>= 1) r += __shfl_down(r, off);
    return r;  // valid in thread 0
}

// Kernel 1: counts[b,i], sums[b,i,f] — register accumulation + DPP reduce.
__global__ __launch_bounds__(512) void k_sums(const float* __restrict__ input,
                                              const int* __restrict__ target,
                                              float* __restrict__ ws) {
    const int b    = blockIdx.y;
    const int w    = threadIdx.x >> 6;
    const int lane = threadIdx.x & 63;
    const int i0   = w * I_PER;
    const int l0   = blockIdx.x * (LL / L_CHUNKS);
    const float* inb = input + (size_t)b * NF * LL;
    const int*   tgb = target + (size_t)b * NI * LL;

    float acc[I_PER][NF];
    float cnt[I_PER];
    #pragma unroll
    for (int ii = 0; ii < I_PER; ++ii) {
        cnt[ii] = 0.f;
        #pragma unroll
        for (int f = 0; f < NF; ++f) acc[ii][f] = 0.f;
    }

    #pragma unroll
    for (int step = 0; step < (LL / L_CHUNKS) / 256; ++step) {  // 2 steps
        const int l = l0 + step * 256 + lane * 4;
        float4 p[NF];
        #pragma unroll
        for (int f = 0; f < NF; ++f)
            p[f] = *reinterpret_cast<const float4*>(inb + f * LL + l);
        #pragma unroll
        for (int ii = 0; ii < I_PER; ++ii) {
            int4 tv = *reinterpret_cast<const int4*>(tgb + (i0 + ii) * LL + l);
            float t0 = (float)tv.x, t1 = (float)tv.y, t2 = (float)tv.z, t3 = (float)tv.w;
            cnt[ii] += (t0 + t1) + (t2 + t3);
            #pragma unroll
            for (int f = 0; f < NF; ++f) {
                float a = acc[ii][f];
                a = fmaf(t0, p[f].x, a);
                a = fmaf(t1, p[f].y, a);
                a = fmaf(t2, p[f].z, a);
                a = fmaf(t3, p[f].w, a);
                acc[ii][f] = a;
            }
        }
    }

    // DPP reduce (VALU-only), totals land in lane 63
    #pragma unroll
    for (int ii = 0; ii < I_PER; ++ii) {
        #pragma unroll
        for (int f = 0; f < NF; ++f) acc[ii][f] = wave_sum63(acc[ii][f]);
        cnt[ii] = wave_sum63(cnt[ii]);
    }
    if (lane == 63) {
        #pragma unroll
        for (int ii = 0; ii < I_PER; ++ii) {
            #pragma unroll
            for (int f = 0; f < NF; ++f)
                atomicAdd(&ws[OFF_SUMS + (b * NI + i0 + ii) * NF + f], acc[ii][f]);
            atomicAdd(&ws[OFF_COUNTS + b * NI + i0 + ii], cnt[ii]);
        }
    }
}

// Kernel 2: variance numerator; means computed inline from sums/counts.
__global__ __launch_bounds__(512) void k_var(const float* __restrict__ input,
                                             const int* __restrict__ target,
                                             const int* __restrict__ n_objects,
                                             float* __restrict__ ws) {
    const int b = blockIdx.y;
    const int n = n_objects[b];
    const int t = threadIdx.x;
    __shared__ float m_lds[NI][NF];
    __shared__ float red[8];
    if (t < NI * NF) {
        int i = t >> 4, f = t & 15;
        float c = ws[OFF_COUNTS + b * NI + i];
        float s = ws[OFF_SUMS + (b * NI + i) * NF + f];
        m_lds[i][f] = (i < n) ? s / (c > 0.f ? c : 1.f) : 0.f;
    }
    __syncthreads();

    const float* inb = input + (size_t)b * NF * LL;
    const int*   tgb = target + (size_t)b * NI * LL;
    const int l = blockIdx.x * 512 + t;   // 32 blocks/batch * 512 = LL

    float p[NF];
    #pragma unroll
    for (int f = 0; f < NF; ++f) p[f] = inb[f * LL + l];

    float acc = 0.f;
    for (int i = 0; i < n; ++i) {
        float tv = (float)tgb[i * LL + l];
        float ss = 0.f;
        #pragma unroll
        for (int f = 0; f < NF; ++f) { float d = p[f] - m_lds[i][f]; ss = fmaf(d, d, ss); }
        float h = fmaxf(sqrtf(ss) - 0.5f, 0.f);
        acc = fmaf(tv, h * h, acc);
    }
    float s = block_sum(acc, red);
    if (t == 0) atomicAdd(&ws[OFF_VNUM + b], s);
}

// Kernel 3: dist + reg + vden + final combine (single block)
__global__ __launch_bounds__(256) void k_final(const int* __restrict__ n_objects,
                                               const float* __restrict__ ws,
                                               float* __restrict__ out) {
    const int t = threadIdx.x;
    __shared__ float m_lds[NI][NF];
    __shared__ float csh[NI];
    __shared__ float red[4];
    float total = 0.f;  // meaningful on thread 0

    for (int b = 0; b < BS; ++b) {
        const int n = n_objects[b];
        __syncthreads();  // protect m_lds/csh reuse across batches
        for (int idx = t; idx < NI * NF; idx += 256) {
            int i = idx >> 4, f = idx & 15;
            float c = ws[OFF_COUNTS + b * NI + i];
            float s = ws[OFF_SUMS + (b * NI + i) * NF + f];
            m_lds[i][f] = (i < n) ? s / (c > 0.f ? c : 1.f) : 0.f;
        }
        if (t < NI) csh[t] = ws[OFF_COUNTS + b * NI + t];
        __syncthreads();

        float vden = 0.f, reg = 0.f;
        if (t < NI && t < n) {
            vden = csh[t];
            float ss = 0.f;
            #pragma unroll
            for (int f = 0; f < NF; ++f) { float m = m_lds[t][f]; ss += m * m; }
            reg = (ss > 0.f) ? sqrtf(ss) : 0.f;
        }
        float dist = 0.f;
        for (int p = t; p < NI * NI; p += 256) {
            int i = p / NI, j = p % NI;
            if (i != j && i < n && j < n) {
                float ss = 0.f;
                #pragma unroll
                for (int f = 0; f < NF; ++f) { float d = m_lds[i][f] - m_lds[j][f]; ss += d * d; }
                float dn = (ss > 0.f) ? sqrtf(ss) : 0.f;
                float h = fmaxf(3.0f - dn, 0.f);  // margin = 2*DELTA_D
                dist += h * h;
            }
        }
        float vden_s = block_sum(vden, red);
        float reg_s  = block_sum(reg, red);
        float dist_s = block_sum(dist, red);
        if (t == 0) {
            float nf = (float)n;
            total += ws[OFF_VNUM + b] / vden_s
                   + ((n > 1) ? dist_s / (nf * (nf - 1.f)) : 0.f)
                   + 0.001f * (reg_s / nf);
        }
    }
    if (t == 0) out[0] = total * (1.0f / (float)BS);
}

extern "C" void kernel_launch(void* const* d_in, const int* in_sizes, int n_in,
                              void* d_out, int out_size, void* d_ws, size_t ws_size,
                              hipStream_t stream) {
    const float* input     = (const float*)d_in[0];
    const int*   target    = (const int*)d_in[1];
    const int*   n_objects = (const int*)d_in[2];
    float* ws  = (float*)d_ws;
    float* out = (float*)d_out;

    hipMemsetAsync(d_ws, 0, WS_ZERO_FLOATS * sizeof(float), stream);

    dim3 gA(L_CHUNKS, BS);
    k_sums<<<gA, 512, 0, stream>>>(input, target, ws);
    dim3 gC(32, BS);
    k_var<<<gC, 512, 0, stream>>>(input, target, n_objects, ws);
    k_final<<<1, 256, 0, stream>>>(n_objects, ws, out);
}

// Round 6
// 90.627 us; speedup vs baseline: 1.3726x; 1.3726x over previous
//
#include <hip/hip_runtime.h>

// Problem dims (fixed by setup_inputs)
#define BS 8
#define NF 16
#define NI 24
#define LL 16384   // 128*128

#define NCH 64            // chunks per batch in k_sums
#define CPX (LL/NCH)      // 256 px per chunk
#define RBLK 32           // blocks per batch in k_rest
#define RTH 512           // threads in k_rest (LL/RBLK px per block)
#define I_PER 3           // instances per wave (8 waves x 3 = 24)

// ws layout (float slots)
#define OFF_PSUMS 0                              // [BS][NCH][NI][NF] 196608
#define OFF_PCNTS (BS*NCH*NI*NF)                 // [BS][NCH][NI]      12288
#define OFF_VNUM  (OFF_PCNTS + BS*NCH*NI)        // [BS]
#define OFF_VDEN  (OFF_VNUM + BS)                // [BS]
#define OFF_DIST  (OFF_VDEN + BS)                // [BS]
#define OFF_REG   (OFF_DIST + BS)                // [BS]
#define OFF_DONE  (OFF_REG + BS)                 // int counter

// Full 64-lane sum via DPP (VALU-only). Result valid in lane 63.
__device__ __forceinline__ float wave_sum63(float v) {
    v += __int_as_float(__builtin_amdgcn_update_dpp(0, __float_as_int(v), 0x111, 0xf, 0xf, true)); // row_shr:1
    v += __int_as_float(__builtin_amdgcn_update_dpp(0, __float_as_int(v), 0x112, 0xf, 0xf, true)); // row_shr:2
    v += __int_as_float(__builtin_amdgcn_update_dpp(0, __float_as_int(v), 0x114, 0xf, 0xf, true)); // row_shr:4
    v += __int_as_float(__builtin_amdgcn_update_dpp(0, __float_as_int(v), 0x118, 0xf, 0xf, true)); // row_shr:8
    v += __int_as_float(__builtin_amdgcn_update_dpp(0, __float_as_int(v), 0x142, 0xa, 0xf, true)); // row_bcast:15
    v += __int_as_float(__builtin_amdgcn_update_dpp(0, __float_as_int(v), 0x143, 0xc, 0xf, true)); // row_bcast:31
    return v;
}

__device__ __forceinline__ float block_sum(float v, volatile float* red) {
    for (int off = 32; off; off >>= 1) v += __shfl_down(v, off);
    __syncthreads();
    if ((threadIdx.x & 63) == 0) red[threadIdx.x >> 6] = v;
    __syncthreads();
    float r = 0.f;
    int nw = blockDim.x >> 6;
    if ((int)threadIdx.x < nw) r = red[threadIdx.x];
    if ((threadIdx.x >> 6) == 0)
        for (int off = 32; off; off >>= 1) r += __shfl_down(r, off);
    return r;  // valid in thread 0
}

// Dispatch 1: per-chunk partial sums/counts, plain stores (no atomics, no init).
__global__ __launch_bounds__(512, 4) void k_sums(const float* __restrict__ input,
                                                 const int* __restrict__ target,
                                                 float* __restrict__ ws) {
    const int b    = blockIdx.y;
    const int c    = blockIdx.x;
    const int w    = threadIdx.x >> 6;
    const int lane = threadIdx.x & 63;
    const int i0   = w * I_PER;
    const int l    = c * CPX + lane * 4;
    const float* inb = input + (size_t)b * NF * LL;
    const int*   tgb = target + (size_t)b * NI * LL;

    // target rows once (3 x int4), then f-outer to keep VGPR < 128
    float tvf[I_PER][4];
    #pragma unroll
    for (int ii = 0; ii < I_PER; ++ii) {
        int4 tv = *reinterpret_cast<const int4*>(tgb + (i0 + ii) * LL + l);
        tvf[ii][0] = (float)tv.x; tvf[ii][1] = (float)tv.y;
        tvf[ii][2] = (float)tv.z; tvf[ii][3] = (float)tv.w;
    }
    float acc[I_PER][NF];
    float cnt[I_PER];
    #pragma unroll
    for (int ii = 0; ii < I_PER; ++ii) {
        cnt[ii] = (tvf[ii][0] + tvf[ii][1]) + (tvf[ii][2] + tvf[ii][3]);
        #pragma unroll
        for (int f = 0; f < NF; ++f) acc[ii][f] = 0.f;
    }
    #pragma unroll
    for (int f = 0; f < NF; ++f) {
        float4 p = *reinterpret_cast<const float4*>(inb + f * LL + l);
        #pragma unroll
        for (int ii = 0; ii < I_PER; ++ii) {
            float a = acc[ii][f];
            a = fmaf(tvf[ii][0], p.x, a);
            a = fmaf(tvf[ii][1], p.y, a);
            a = fmaf(tvf[ii][2], p.z, a);
            a = fmaf(tvf[ii][3], p.w, a);
            acc[ii][f] = a;
        }
    }

    #pragma unroll
    for (int ii = 0; ii < I_PER; ++ii) {
        #pragma unroll
        for (int f = 0; f < NF; ++f) acc[ii][f] = wave_sum63(acc[ii][f]);
        cnt[ii] = wave_sum63(cnt[ii]);
    }
    if (lane == 63) {
        float* ps = ws + OFF_PSUMS + (((size_t)b * NCH + c) * NI + i0) * NF;
        float* pc = ws + OFF_PCNTS + ((size_t)b * NCH + c) * NI + i0;
        #pragma unroll
        for (int ii = 0; ii < I_PER; ++ii) {
            #pragma unroll
            for (int f = 0; f < NF; ++f) ps[ii * NF + f] = acc[ii][f];
            pc[ii] = cnt[ii];
        }
    }
    // re-init cross-dispatch scalars every call
    if (c == 0 && threadIdx.x == 0) {
        ws[OFF_VNUM + b] = 0.f;
        if (b == 0) *(int*)(ws + OFF_DONE) = 0;
    }
}

// Dispatch 2: means from partials; var term; batch-local dist/reg/vden; last block combines.
__global__ __launch_bounds__(512, 4) void k_rest(const float* __restrict__ input,
                                                 const int* __restrict__ target,
                                                 const int* __restrict__ n_objects,
                                                 float* __restrict__ ws,
                                                 float* __restrict__ out) {
    const int b = blockIdx.y;
    const int t = threadIdx.x;
    const int n = n_objects[b];
    __shared__ float m_lds[NI][NF];
    __shared__ float c_lds[NI];
    __shared__ float red[8];
    __shared__ int amLast;

    // Phase A: reduce NCH partial slots (coalesced 384-float rows)
    float rawsum = 0.f;
    if (t < NI * NF) {
        const float* ps = ws + OFF_PSUMS + (size_t)b * NCH * NI * NF + t;
        #pragma unroll 8
        for (int c = 0; c < NCH; ++c) rawsum += ps[(size_t)c * NI * NF];
    } else if (t >= NI * NF && t < NI * NF + NI) {
        const float* pc = ws + OFF_PCNTS + (size_t)b * NCH * NI + (t - NI * NF);
        float s = 0.f;
        #pragma unroll 8
        for (int c = 0; c < NCH; ++c) s += pc[c * NI];
        c_lds[t - NI * NF] = s;
    }
    __syncthreads();
    if (t < NI * NF) {
        int i = t >> 4;
        float cv = c_lds[i];
        m_lds[i][t & 15] = (i < n) ? rawsum / (cv > 0.f ? cv : 1.f) : 0.f;
    }
    __syncthreads();

    // Phase B: variance numerator, 1 px/thread
    const float* inb = input + (size_t)b * NF * LL;
    const int*   tgb = target + (size_t)b * NI * LL;
    const int l = blockIdx.x * RTH + t;
    float p[NF];
    #pragma unroll
    for (int f = 0; f < NF; ++f) p[f] = inb[f * LL + l];
    float acc = 0.f;
    for (int i = 0; i < n; ++i) {
        float tv = (float)tgb[i * LL + l];
        float ss = 0.f;
        #pragma unroll
        for (int f = 0; f < NF; ++f) { float d = p[f] - m_lds[i][f]; ss = fmaf(d, d, ss); }
        float h = fmaxf(sqrtf(ss) - 0.5f, 0.f);
        acc = fmaf(tv, h * h, acc);
    }
    float vsum = block_sum(acc, red);

    // block x=0: batch-local dist/reg/vden (means already in LDS)
    if (blockIdx.x == 0) {
        float vden = 0.f, reg = 0.f;
        if (t < NI && t < n) {
            vden = c_lds[t];
            float ss = 0.f;
            #pragma unroll
            for (int f = 0; f < NF; ++f) { float m = m_lds[t][f]; ss += m * m; }
            reg = (ss > 0.f) ? sqrtf(ss) : 0.f;
        }
        float dist = 0.f;
        for (int pp = t; pp < NI * NI; pp += RTH) {
            int i = pp / NI, j = pp % NI;
            if (i != j && i < n && j < n) {
                float ss = 0.f;
                #pragma unroll
                for (int f = 0; f < NF; ++f) { float d = m_lds[i][f] - m_lds[j][f]; ss += d * d; }
                float dn = (ss > 0.f) ? sqrtf(ss) : 0.f;
                float h = fmaxf(3.0f - dn, 0.f);   // margin = 2*DELTA_D
                dist += h * h;
            }
        }
        float vden_s = block_sum(vden, red);
        float reg_s  = block_sum(reg, red);
        float dist_s = block_sum(dist, red);
        if (t == 0) {
            float nf = (float)n;
            __hip_atomic_store(&ws[OFF_VDEN + b], vden_s, __ATOMIC_RELAXED, __HIP_MEMORY_SCOPE_AGENT);
            __hip_atomic_store(&ws[OFF_REG + b], reg_s / nf, __ATOMIC_RELAXED, __HIP_MEMORY_SCOPE_AGENT);
            __hip_atomic_store(&ws[OFF_DIST + b],
                               (n > 1) ? dist_s / (nf * (nf - 1.f)) : 0.f,
                               __ATOMIC_RELAXED, __HIP_MEMORY_SCOPE_AGENT);
        }
    }

    // combine: last block to finish does the scalar reduction
    if (t == 0) {
        atomicAdd(&ws[OFF_VNUM + b], vsum);
        __threadfence();
        int prev = atomicAdd((int*)(ws + OFF_DONE), 1);
        amLast = (prev == RBLK * BS - 1) ? 1 : 0;
    }
    __syncthreads();
    if (amLast && t == 0) {
        __threadfence();
        float total = 0.f;
        for (int b2 = 0; b2 < BS; ++b2) {
            float vn = __hip_atomic_load(&ws[OFF_VNUM + b2], __ATOMIC_RELAXED, __HIP_MEMORY_SCOPE_AGENT);
            float vd = __hip_atomic_load(&ws[OFF_VDEN + b2], __ATOMIC_RELAXED, __HIP_MEMORY_SCOPE_AGENT);
            float dt = __hip_atomic_load(&ws[OFF_DIST + b2], __ATOMIC_RELAXED, __HIP_MEMORY_SCOPE_AGENT);
            float rg = __hip_atomic_load(&ws[OFF_REG + b2], __ATOMIC_RELAXED, __HIP_MEMORY_SCOPE_AGENT);
            total += vn / vd + dt + 0.001f * rg;
        }
        out[0] = total * (1.0f / (float)BS);
    }
}

extern "C" void kernel_launch(void* const* d_in, const int* in_sizes, int n_in,
                              void* d_out, int out_size, void* d_ws, size_t ws_size,
                              hipStream_t stream) {
    const float* input     = (const float*)d_in[0];
    const int*   target    = (const int*)d_in[1];
    const int*   n_objects = (const int*)d_in[2];
    float* ws  = (float*)d_ws;
    float* out = (float*)d_out;

    dim3 gA(NCH, BS);
    k_sums<<<gA, 512, 0, stream>>>(input, target, ws);
    dim3 gB(RBLK, BS);
    k_rest<<<gB, 512, 0, stream>>>(input, target, n_objects, ws, out);
}